// Round 1
// baseline (940.504 us; speedup 1.0000x reference)
//
#include <hip/hip_runtime.h>
#include <math.h>

#define HW_TOT 5440
#define NQ 4096
#define DM 256

// ---------------------------------------------------------------------------
// GEMM: C[M,N] = A[M,K] @ W[N,K]^T + bias[N]
// BM=64, BN=64, BK=32, 256 threads, 4x4 per thread. M%64==0, N%64==0, K%32==0.
// ---------------------------------------------------------------------------
__global__ __launch_bounds__(256) void gemm_nt(const float* __restrict__ A,
    const float* __restrict__ W, const float* __restrict__ bias,
    float* __restrict__ C, int M, int N, int Kd)
{
    __shared__ float As[32][68];
    __shared__ float Ws[32][68];
    const int bm = blockIdx.y * 64, bn = blockIdx.x * 64;
    const int t  = threadIdx.x;
    const int tx = t & 15, ty = t >> 4;
    const int mrow = t >> 3;           // 0..31
    const int kcol = (t & 7) << 2;     // 0,4,..,28
    float acc[4][4] = {};
    for (int k0 = 0; k0 < Kd; k0 += 32) {
#pragma unroll
        for (int half = 0; half < 2; ++half) {
            int m = mrow + half * 32;
            float4 a = *(const float4*)&A[(size_t)(bm + m) * Kd + k0 + kcol];
            As[kcol + 0][m] = a.x; As[kcol + 1][m] = a.y;
            As[kcol + 2][m] = a.z; As[kcol + 3][m] = a.w;
            float4 w = *(const float4*)&W[(size_t)(bn + m) * Kd + k0 + kcol];
            Ws[kcol + 0][m] = w.x; Ws[kcol + 1][m] = w.y;
            Ws[kcol + 2][m] = w.z; Ws[kcol + 3][m] = w.w;
        }
        __syncthreads();
#pragma unroll
        for (int k = 0; k < 32; ++k) {
            float4 av = *(const float4*)&As[k][ty << 2];
            float4 wv = *(const float4*)&Ws[k][tx << 2];
            float aa[4] = {av.x, av.y, av.z, av.w};
            float ww[4] = {wv.x, wv.y, wv.z, wv.w};
#pragma unroll
            for (int i = 0; i < 4; ++i)
#pragma unroll
                for (int j = 0; j < 4; ++j) acc[i][j] += aa[i] * ww[j];
        }
        __syncthreads();
    }
#pragma unroll
    for (int i = 0; i < 4; ++i) {
        int m = bm + (ty << 2) + i;
#pragma unroll
        for (int j = 0; j < 4; ++j) {
            int n = bn + (tx << 2) + j;
            C[(size_t)m * N + n] = acc[i][j] + bias[n];
        }
    }
}

// ---------------------------------------------------------------------------
// Depthwise 3x3 conv SAME, channel-last (B,HW,256). Block = one (b,pos) row.
// Weight shared across k: channel c -> d = c & 63.
// ---------------------------------------------------------------------------
__global__ __launch_bounds__(256) void dwconv(const float* __restrict__ val,
    const float* __restrict__ cw, const float* __restrict__ cb,
    const int* __restrict__ shapes, const int* __restrict__ starts,
    float* __restrict__ out)
{
    __shared__ float wsm[576];
    __shared__ float bsm[64];
    const int t = threadIdx.x;
    if (t < 64) bsm[t] = cb[t];
    for (int i = t; i < 576; i += 256) wsm[i] = cw[i];
    __syncthreads();

    const int idx = blockIdx.x;                 // b*HW + pos
    const int b = idx / HW_TOT;
    const int pos = idx - b * HW_TOT;
    const int s1 = starts[1], s2 = starts[2], s3 = starts[3];
    const int lv = (pos >= s3) ? 3 : (pos >= s2) ? 2 : (pos >= s1) ? 1 : 0;
    const int st = (lv == 0) ? 0 : (lv == 1) ? s1 : (lv == 2) ? s2 : s3;
    const int Hh = shapes[2 * lv], Ww = shapes[2 * lv + 1];
    const int rel = pos - st;
    const int y = rel / Ww;
    const int x = rel - y * Ww;
    const int c = t;
    const int d = c & 63;
    float acc = bsm[d];
    const float* vb = val + ((size_t)(b * HW_TOT + st)) * DM + c;
#pragma unroll
    for (int ky = -1; ky <= 1; ++ky) {
        int ny = y + ky;
        if (ny < 0 || ny >= Hh) continue;
#pragma unroll
        for (int kx = -1; kx <= 1; ++kx) {
            int nx = x + kx;
            if (nx < 0 || nx >= Ww) continue;
            acc += wsm[d * 9 + (ky + 1) * 3 + (kx + 1)] * vb[(size_t)(ny * Ww + nx) * DM];
        }
    }
    out[(size_t)idx * DM + c] = acc;
}

// ---------------------------------------------------------------------------
// Fused: bilinear sampling + x_proj + dt_proj + selective scan (last step only)
// + LayerNorm. One wave (64 threads) per (b,q,k); lane = d.
// ---------------------------------------------------------------------------
__global__ __launch_bounds__(64) void fused_ss(
    const float* __restrict__ conv, const float* __restrict__ offs_buf,
    const float* __restrict__ st_buf, const float* __restrict__ ref,
    const int* __restrict__ shapes, const int* __restrict__ starts,
    const float* __restrict__ xpw, const float* __restrict__ dtw,
    const float* __restrict__ dtb, const float* __restrict__ A_logs,
    const float* __restrict__ Ds, const float* __restrict__ ln_g,
    const float* __restrict__ ln_b, float* __restrict__ yout)
{
    const int wid = blockIdx.x;
    const int k  = wid & 3;
    const int bq = wid >> 2;              // b*NQ + q
    const int b  = bq >> 12;              // / NQ
    const int d  = threadIdx.x;

    __shared__ float ss_lds[64][17];
    __shared__ float dts_lds[4][17];
    __shared__ float Bs_lds[16][17];
    __shared__ float Cs_lds[16];

    int sh[8], stt[4];
#pragma unroll
    for (int i = 0; i < 8; ++i) sh[i] = shapes[i];
#pragma unroll
    for (int i = 0; i < 4; ++i) stt[i] = starts[i];

    const float* offp = offs_buf + (size_t)bq * 128 + k * 32;
    const float* refp = ref + (size_t)bq * 8;

    float ss[17];
#pragma unroll
    for (int s = 0; s < 16; ++s) {
        const int lv = s >> 2;
        const int Hh = sh[2 * lv], Ww = sh[2 * lv + 1];
        // gx = ((2*loc-1)+1)*0.5*W - 0.5 = loc*W - 0.5 ; loc = ref + off/W
        float gx = refp[2 * lv + 0] * (float)Ww + offp[2 * s + 0] - 0.5f;
        float gy = refp[2 * lv + 1] * (float)Hh + offp[2 * s + 1] - 0.5f;
        float x0f = floorf(gx), y0f = floorf(gy);
        int ix0 = (int)x0f, iy0 = (int)y0f;
        float wx = gx - x0f, wy = gy - y0f;
        const float* base = conv + ((size_t)(b * HW_TOT + stt[lv])) * DM + k * 64 + d;
        float acc = 0.f;
        bool vx0 = (ix0 >= 0) & (ix0 < Ww);
        bool vx1 = (ix0 + 1 >= 0) & (ix0 + 1 < Ww);
        if (iy0 >= 0 && iy0 < Hh) {
            const float* r0 = base + (size_t)iy0 * Ww * DM;
            if (vx0) acc += (1.f - wx) * (1.f - wy) * r0[(size_t)ix0 * DM];
            if (vx1) acc += wx * (1.f - wy) * r0[(size_t)(ix0 + 1) * DM];
        }
        if (iy0 + 1 >= 0 && iy0 + 1 < Hh) {
            const float* r1 = base + (size_t)(iy0 + 1) * Ww * DM;
            if (vx0) acc += (1.f - wx) * wy * r1[(size_t)ix0 * DM];
            if (vx1) acc += wx * wy * r1[(size_t)(ix0 + 1) * DM];
        }
        ss[s] = acc;
    }
    ss[16] = st_buf[(size_t)bq * 256 + k * 64 + d];

#pragma unroll
    for (int l = 0; l < 17; ++l) ss_lds[d][l] = ss[l];
    __syncthreads();

    // x_dbl: rows 0..19 (dts + Bs) for all 17 steps; rows 20..35 (Cs) at t=16.
    const float* xp = xpw + k * 36 * 64;
#pragma unroll
    for (int it = 0; it < 6; ++it) {
        int tsk = d + (it << 6);
        if (tsk < 356) {
            int c, l;
            if (tsk < 340) { c = tsk / 17; l = tsk - c * 17; }
            else           { c = tsk - 320; l = 16; }
            const float* row = xp + c * 64;
            float acc = 0.f;
#pragma unroll
            for (int dd = 0; dd < 64; dd += 4) {
                float4 rv = *(const float4*)&row[dd];
                acc += rv.x * ss_lds[dd + 0][l] + rv.y * ss_lds[dd + 1][l]
                     + rv.z * ss_lds[dd + 2][l] + rv.w * ss_lds[dd + 3][l];
            }
            if (c < 4)       dts_lds[c][l] = acc;
            else if (c < 20) Bs_lds[c - 4][l] = acc;
            else             Cs_lds[c - 20] = acc;
        }
    }
    __syncthreads();

    // selective scan, per-lane d; only final C.h is needed.
    const int kd = k * 64 + d;
    float Avals[16];
    const float* Ap = A_logs + (size_t)kd * 16;
#pragma unroll
    for (int n = 0; n < 16; ++n) Avals[n] = -__expf(Ap[n]);
    float dtwr[4];
#pragma unroll
    for (int r = 0; r < 4; ++r) dtwr[r] = dtw[kd * 4 + r];
    const float dtbv = dtb[kd];
    float h[16];
#pragma unroll
    for (int n = 0; n < 16; ++n) h[n] = 0.f;
#pragma unroll
    for (int t = 0; t < 17; ++t) {
        float xv = dtwr[0] * dts_lds[0][t] + dtwr[1] * dts_lds[1][t]
                 + dtwr[2] * dts_lds[2][t] + dtwr[3] * dts_lds[3][t] + dtbv;
        float delta = (xv > 20.f) ? xv : log1pf(__expf(xv));
        float du = delta * ss[t];
#pragma unroll
        for (int n = 0; n < 16; ++n)
            h[n] = __expf(delta * Avals[n]) * h[n] + du * Bs_lds[n][t];
    }
    float yv = 0.f;
#pragma unroll
    for (int n = 0; n < 16; ++n) yv += h[n] * Cs_lds[n];
    yv += ss[16] * Ds[kd];

    // LayerNorm over the 64 lanes (d dimension)
    float mu = yv;
#pragma unroll
    for (int off = 32; off; off >>= 1) mu += __shfl_xor(mu, off);
    mu *= (1.f / 64.f);
    float dv = yv - mu;
    float var = dv * dv;
#pragma unroll
    for (int off = 32; off; off >>= 1) var += __shfl_xor(var, off);
    var *= (1.f / 64.f);
    float o = dv / sqrtf(var + 1e-5f) * ln_g[d] + ln_b[d];
    yout[(size_t)bq * 256 + kd] = o;
}

// ---------------------------------------------------------------------------
extern "C" void kernel_launch(void* const* d_in, const int* in_sizes, int n_in,
                              void* d_out, int out_size, void* d_ws, size_t ws_size,
                              hipStream_t stream)
{
    const float* query   = (const float*)d_in[0];
    const float* refpts  = (const float*)d_in[1];
    const float* inflat  = (const float*)d_in[2];
    const int*   shapes  = (const int*)d_in[3];
    const int*   starts  = (const int*)d_in[4];
    const float* W_value = (const float*)d_in[5];
    const float* b_value = (const float*)d_in[6];
    const float* W_offs  = (const float*)d_in[7];
    const float* b_offs  = (const float*)d_in[8];
    const float* W_query = (const float*)d_in[9];
    const float* b_query = (const float*)d_in[10];
    const float* W_out   = (const float*)d_in[11];
    const float* b_out   = (const float*)d_in[12];
    const float* conv_w  = (const float*)d_in[13];
    const float* conv_b  = (const float*)d_in[14];
    const float* xpw     = (const float*)d_in[15];
    const float* dtw     = (const float*)d_in[16];
    const float* dtb     = (const float*)d_in[17];
    const float* A_logs  = (const float*)d_in[18];
    const float* Dsp     = (const float*)d_in[19];
    const float* ln_g    = (const float*)d_in[20];
    const float* ln_b    = (const float*)d_in[21];
    float* out = (float*)d_out;

    // workspace layout (f32): value(10880*256) | conv(10880*256) |
    //                         offs(8192*128)   | st(8192*256) | y(8192*256)
    float* value   = (float*)d_ws;
    float* convout = value   + (size_t)10880 * 256;
    float* offsb   = convout + (size_t)10880 * 256;
    float* stb     = offsb   + (size_t)8192 * 128;
    float* ybuf    = stb     + (size_t)8192 * 256;

    // 1. value projection
    gemm_nt<<<dim3(256 / 64, 10880 / 64), 256, 0, stream>>>(
        inflat, W_value, b_value, value, 10880, 256, 256);
    // 2. depthwise conv
    dwconv<<<10880, 256, 0, stream>>>(value, conv_w, conv_b, shapes, starts, convout);
    // 3. offsets projection
    gemm_nt<<<dim3(128 / 64, 8192 / 64), 256, 0, stream>>>(
        query, W_offs, b_offs, offsb, 8192, 128, 256);
    // 4. query (st) projection
    gemm_nt<<<dim3(256 / 64, 8192 / 64), 256, 0, stream>>>(
        query, W_query, b_query, stb, 8192, 256, 256);
    // 5. fused sampling + selective scan + LN
    fused_ss<<<32768, 64, 0, stream>>>(convout, offsb, stb, refpts, shapes, starts,
                                       xpw, dtw, dtb, A_logs, Dsp, ln_g, ln_b, ybuf);
    // 6. output projection
    gemm_nt<<<dim3(256 / 64, 8192 / 64), 256, 0, stream>>>(
        ybuf, W_out, b_out, out, 8192, 256, 256);
}